// Round 2
// baseline (210.466 us; speedup 1.0000x reference)
//
#include <hip/hip_runtime.h>

// One-level separable wavelet filterbank (maxflat), periodic extension.
// x: [8,3,1024,1024] f32 -> out: [4, 8,3,512,512] f32 (LL, LH, HL, HH)
//
// Round 5: register-prefetch pipeline with a SINGLE LDS buffer.
// Round-4 post-mortem: double-buffered LDS (39.9 KB) halved blocks/CU
// (8->4) and the 4x-smaller grid removed cross-block stagger -> BW fell.
// Fix: the prefetched tile lives in REGISTERS across the barrier, so one
// 19.9 KB buffer suffices (8 blocks/CU). Each block does NT=2 tiles:
// tile t+1's global loads are issued before PHASE2(t), so HBM stays busy
// during phase-2 compute; one extra barrier decouples the LDS overwrite.

constexpr int H = 1024, W = 1024;
constexpr int NIMG = 24;            // 8*3
constexpr int HOUT = 512, WOUT = 512;
constexpr int TO = 32;              // output tile edge
constexpr int NT = 2;               // tiles per block along x
constexpr int RIN = 69;             // input rows needed: 2*0-4 .. 2*31+2
constexpr int PAD = 36;             // keeps rows 16B-aligned; 4-bank shift/row
constexpr int NITEM = RIN * 4;      // 276 phase-1 work items per tile

__global__ __launch_bounds__(256, 8)   // pin VGPR<=64 so 8 blocks/CU is reachable
void wfb_kernel(const float* __restrict__ x, float* __restrict__ out) {
    __shared__ float s_L[RIN][PAD];     // row-lowpass at even cols
    __shared__ float s_H[RIN][PAD];     // row-highpass at even cols

    // h (len 5, ext 2) and h1 (len 7, ext 4), exact maxflat values
    const float h0c[5] = {0.125f, 0.35355339059327373f, 1.25f,
                          0.35355339059327373f, 0.125f};
    const float h1c[7] = {0.025888347648318447f,  0.07322330470336313f,
                          -0.06878156646177083f, -0.8535533905932737f,
                          -0.06878156646177083f,  0.07322330470336313f,
                          0.025888347648318447f};

    const int tid = threadIdx.x;
    const int img = blockIdx.z;
    const int r0 = blockIdx.y * TO;          // output-row offset (fixed)
    const int c0b = blockIdx.x * (NT * TO);  // block's first output col
    const float* __restrict__ xin = x + (size_t)img * H * W;
    const int rbase = 2 * r0 - 4;

    // ---- per-thread phase-1 item state (1 item; threads 0..19 get a 2nd) ----
    const int m0 = tid;
    const int m1 = tid + 256;
    const bool has1 = (m1 < NITEM);          // 20 threads, all in wave 0
    const int r_0 = m0 >> 2, g_0 = m0 & 3;
    const int r_1 = (has1 ? m1 : m0) >> 2, g_1 = (has1 ? m1 : m0) & 3;
    const float* __restrict__ rowp0 = xin + (size_t)((rbase + r_0) & (H - 1)) * W;
    const float* __restrict__ rowp1 = xin + (size_t)((rbase + r_1) & (H - 1)) * W;

    float v0[24], v1[24];   // prefetched inputs, live across barriers

    auto LOAD = [&](int t) {
        const int cbase = 2 * (c0b + t * TO) - 4;  // multiple of 4 -> f4-aligned
        {
            const int b0 = cbase + 16 * g_0;
            #pragma unroll
            for (int q = 0; q < 6; ++q) {
                int gc = (b0 + 4 * q) & (W - 1);   // periodic, keeps 16B align
                float4 f = *(const float4*)(rowp0 + gc);
                v0[4*q+0] = f.x; v0[4*q+1] = f.y;
                v0[4*q+2] = f.z; v0[4*q+3] = f.w;
            }
        }
        if (has1) {
            const int b0 = cbase + 16 * g_1;
            #pragma unroll
            for (int q = 0; q < 6; ++q) {
                int gc = (b0 + 4 * q) & (W - 1);
                float4 f = *(const float4*)(rowp1 + gc);
                v1[4*q+0] = f.x; v1[4*q+1] = f.y;
                v1[4*q+2] = f.z; v1[4*q+3] = f.w;
            }
        }
    };

    auto ROWFILT = [&]() {   // consume v0/v1 -> LDS (single buffer)
        {
            float Lo[8], Ho[8];
            #pragma unroll
            for (int u = 0; u < 8; ++u) {
                const float* p = v0 + 2 * u;
                Lo[u] = h0c[0]*p[2] + h0c[1]*p[3] + h0c[2]*p[4]
                      + h0c[3]*p[5] + h0c[4]*p[6];
                Ho[u] = h1c[0]*p[0] + h1c[1]*p[1] + h1c[2]*p[2] + h1c[3]*p[3]
                      + h1c[4]*p[4] + h1c[5]*p[5] + h1c[6]*p[6];
            }
            const int j0 = 8 * g_0;
            *(float4*)&s_L[r_0][j0]     = make_float4(Lo[0],Lo[1],Lo[2],Lo[3]);
            *(float4*)&s_L[r_0][j0 + 4] = make_float4(Lo[4],Lo[5],Lo[6],Lo[7]);
            *(float4*)&s_H[r_0][j0]     = make_float4(Ho[0],Ho[1],Ho[2],Ho[3]);
            *(float4*)&s_H[r_0][j0 + 4] = make_float4(Ho[4],Ho[5],Ho[6],Ho[7]);
        }
        if (has1) {
            float Lo[8], Ho[8];
            #pragma unroll
            for (int u = 0; u < 8; ++u) {
                const float* p = v1 + 2 * u;
                Lo[u] = h0c[0]*p[2] + h0c[1]*p[3] + h0c[2]*p[4]
                      + h0c[3]*p[5] + h0c[4]*p[6];
                Ho[u] = h1c[0]*p[0] + h1c[1]*p[1] + h1c[2]*p[2] + h1c[3]*p[3]
                      + h1c[4]*p[4] + h1c[5]*p[5] + h1c[6]*p[6];
            }
            const int j0 = 8 * g_1;
            *(float4*)&s_L[r_1][j0]     = make_float4(Lo[0],Lo[1],Lo[2],Lo[3]);
            *(float4*)&s_L[r_1][j0 + 4] = make_float4(Lo[4],Lo[5],Lo[6],Lo[7]);
            *(float4*)&s_H[r_1][j0]     = make_float4(Ho[0],Ho[1],Ho[2],Ho[3]);
            *(float4*)&s_H[r_1][j0 + 4] = make_float4(Ho[4],Ho[5],Ho[6],Ho[7]);
        }
    };

    // ---- phase-2 per-thread geometry (fixed across tiles) ----
    constexpr size_t SB = (size_t)NIMG * HOUT * WOUT;  // per-subband stride
    float* __restrict__ o = out + (size_t)img * HOUT * WOUT;
    const int i_  = tid >> 3;          // 0..31 output row in tile
    const int jj_ = (tid & 7) * 4;     // 0,4,...,28 output col in tile

    auto PHASE2 = [&](int t) {
        const int c0 = c0b + t * TO;
        float LLx=0,LLy=0,LLz=0,LLw=0, HLx=0,HLy=0,HLz=0,HLw=0;
        float LHx=0,LHy=0,LHz=0,LHw=0, HHx=0,HHy=0,HHz=0,HHw=0;
        #pragma unroll
        for (int k = 0; k < 5; ++k) {
            float4 a = *(const float4*)&s_L[2*i_ + 2 + k][jj_];
            float4 b = *(const float4*)&s_H[2*i_ + 2 + k][jj_];
            LLx += h0c[k]*a.x; LLy += h0c[k]*a.y; LLz += h0c[k]*a.z; LLw += h0c[k]*a.w;
            HLx += h0c[k]*b.x; HLy += h0c[k]*b.y; HLz += h0c[k]*b.z; HLw += h0c[k]*b.w;
        }
        #pragma unroll
        for (int k = 0; k < 7; ++k) {
            float4 a = *(const float4*)&s_L[2*i_ + k][jj_];
            float4 b = *(const float4*)&s_H[2*i_ + k][jj_];
            LHx += h1c[k]*a.x; LHy += h1c[k]*a.y; LHz += h1c[k]*a.z; LHw += h1c[k]*a.w;
            HHx += h1c[k]*b.x; HHy += h1c[k]*b.y; HHz += h1c[k]*b.z; HHw += h1c[k]*b.w;
        }
        size_t off = (size_t)(r0 + i_) * WOUT + (c0 + jj_);
        *(float4*)(o + 0 * SB + off) = make_float4(LLx, LLy, LLz, LLw);
        *(float4*)(o + 1 * SB + off) = make_float4(LHx, LHy, LHz, LHw);
        *(float4*)(o + 2 * SB + off) = make_float4(HLx, HLy, HLz, HLw);
        *(float4*)(o + 3 * SB + off) = make_float4(HHx, HHy, HHz, HHw);
    };

    // ---- pipeline (single LDS buffer; prefetch carried in registers) ----
    LOAD(0);
    ROWFILT();                 // tile 0 -> LDS (waits on tile-0 loads)
    LOAD(1);                   // tile-1 loads go in flight
    __syncthreads();

    #pragma unroll
    for (int t = 0; t < NT; ++t) {
        PHASE2(t);             // reads LDS; next tile's loads in flight
        if (t + 1 < NT) {
            __syncthreads();   // all reads of LDS done
            ROWFILT();         // consume v -> overwrite LDS with tile t+1
            if (t + 2 < NT) LOAD(t + 2);
            __syncthreads();   // LDS ready
        }
    }
}

extern "C" void kernel_launch(void* const* d_in, const int* in_sizes, int n_in,
                              void* d_out, int out_size, void* d_ws, size_t ws_size,
                              hipStream_t stream) {
    const float* x = (const float*)d_in[0];
    float* out = (float*)d_out;
    dim3 grid(WOUT / (TO * NT), HOUT / TO, NIMG);   // 8 x 16 x 24
    wfb_kernel<<<grid, dim3(256), 0, stream>>>(x, out);
}

// Round 3
// 183.168 us; speedup vs baseline: 1.1490x; 1.1490x over previous
//
#include <hip/hip_runtime.h>

// One-level separable wavelet filterbank (maxflat), periodic extension.
// x: [8,3,1024,1024] f32 -> out: [4, 8,3,512,512] f32 (LL, LH, HL, HH)
//
// Round 6: round-5 pipeline with the spill bug fixed.
// Round-5 post-mortem: __launch_bounds__(256,8) capped VGPR at 32, but
// the register-prefetch pipeline keeps 48 floats (v0+v1) live across
// barriers -> scratch spills (WRITE_SIZE 98->191 MB, VALUBusy ~1%).
// Fix: plain __launch_bounds__(256); VGPR floats to ~56 (round-4 value,
// no spills). Structure unchanged: single 19.9 KB LDS buffer (8 blocks/CU
// reachable), NT=2 tiles/block, tile t+1's global loads issued before
// PHASE2(t) so HBM stays busy during phase-2 compute.

constexpr int H = 1024, W = 1024;
constexpr int NIMG = 24;            // 8*3
constexpr int HOUT = 512, WOUT = 512;
constexpr int TO = 32;              // output tile edge
constexpr int NT = 2;               // tiles per block along x
constexpr int RIN = 69;             // input rows needed: 2*0-4 .. 2*31+2
constexpr int PAD = 36;             // keeps rows 16B-aligned; 4-bank shift/row
constexpr int NITEM = RIN * 4;      // 276 phase-1 work items per tile

__global__ __launch_bounds__(256)
void wfb_kernel(const float* __restrict__ x, float* __restrict__ out) {
    __shared__ float s_L[RIN][PAD];     // row-lowpass at even cols
    __shared__ float s_H[RIN][PAD];     // row-highpass at even cols

    // h (len 5, ext 2) and h1 (len 7, ext 4), exact maxflat values
    const float h0c[5] = {0.125f, 0.35355339059327373f, 1.25f,
                          0.35355339059327373f, 0.125f};
    const float h1c[7] = {0.025888347648318447f,  0.07322330470336313f,
                          -0.06878156646177083f, -0.8535533905932737f,
                          -0.06878156646177083f,  0.07322330470336313f,
                          0.025888347648318447f};

    const int tid = threadIdx.x;
    const int img = blockIdx.z;
    const int r0 = blockIdx.y * TO;          // output-row offset (fixed)
    const int c0b = blockIdx.x * (NT * TO);  // block's first output col
    const float* __restrict__ xin = x + (size_t)img * H * W;
    const int rbase = 2 * r0 - 4;

    // ---- per-thread phase-1 item state (1 item; threads 0..19 get a 2nd) ----
    const int m0 = tid;
    const int m1 = tid + 256;
    const bool has1 = (m1 < NITEM);          // 20 threads, all in wave 0
    const int r_0 = m0 >> 2, g_0 = m0 & 3;
    const int r_1 = (has1 ? m1 : m0) >> 2, g_1 = (has1 ? m1 : m0) & 3;
    const float* __restrict__ rowp0 = xin + (size_t)((rbase + r_0) & (H - 1)) * W;
    const float* __restrict__ rowp1 = xin + (size_t)((rbase + r_1) & (H - 1)) * W;

    float v0[24], v1[24];   // prefetched inputs, live across barriers

    auto LOAD = [&](int t) {
        const int cbase = 2 * (c0b + t * TO) - 4;  // multiple of 4 -> f4-aligned
        {
            const int b0 = cbase + 16 * g_0;
            #pragma unroll
            for (int q = 0; q < 6; ++q) {
                int gc = (b0 + 4 * q) & (W - 1);   // periodic, keeps 16B align
                float4 f = *(const float4*)(rowp0 + gc);
                v0[4*q+0] = f.x; v0[4*q+1] = f.y;
                v0[4*q+2] = f.z; v0[4*q+3] = f.w;
            }
        }
        if (has1) {
            const int b0 = cbase + 16 * g_1;
            #pragma unroll
            for (int q = 0; q < 6; ++q) {
                int gc = (b0 + 4 * q) & (W - 1);
                float4 f = *(const float4*)(rowp1 + gc);
                v1[4*q+0] = f.x; v1[4*q+1] = f.y;
                v1[4*q+2] = f.z; v1[4*q+3] = f.w;
            }
        }
    };

    auto ROWFILT = [&]() {   // consume v0/v1 -> LDS (single buffer)
        {
            float Lo[8], Ho[8];
            #pragma unroll
            for (int u = 0; u < 8; ++u) {
                const float* p = v0 + 2 * u;
                Lo[u] = h0c[0]*p[2] + h0c[1]*p[3] + h0c[2]*p[4]
                      + h0c[3]*p[5] + h0c[4]*p[6];
                Ho[u] = h1c[0]*p[0] + h1c[1]*p[1] + h1c[2]*p[2] + h1c[3]*p[3]
                      + h1c[4]*p[4] + h1c[5]*p[5] + h1c[6]*p[6];
            }
            const int j0 = 8 * g_0;
            *(float4*)&s_L[r_0][j0]     = make_float4(Lo[0],Lo[1],Lo[2],Lo[3]);
            *(float4*)&s_L[r_0][j0 + 4] = make_float4(Lo[4],Lo[5],Lo[6],Lo[7]);
            *(float4*)&s_H[r_0][j0]     = make_float4(Ho[0],Ho[1],Ho[2],Ho[3]);
            *(float4*)&s_H[r_0][j0 + 4] = make_float4(Ho[4],Ho[5],Ho[6],Ho[7]);
        }
        if (has1) {
            float Lo[8], Ho[8];
            #pragma unroll
            for (int u = 0; u < 8; ++u) {
                const float* p = v1 + 2 * u;
                Lo[u] = h0c[0]*p[2] + h0c[1]*p[3] + h0c[2]*p[4]
                      + h0c[3]*p[5] + h0c[4]*p[6];
                Ho[u] = h1c[0]*p[0] + h1c[1]*p[1] + h1c[2]*p[2] + h1c[3]*p[3]
                      + h1c[4]*p[4] + h1c[5]*p[5] + h1c[6]*p[6];
            }
            const int j0 = 8 * g_1;
            *(float4*)&s_L[r_1][j0]     = make_float4(Lo[0],Lo[1],Lo[2],Lo[3]);
            *(float4*)&s_L[r_1][j0 + 4] = make_float4(Lo[4],Lo[5],Lo[6],Lo[7]);
            *(float4*)&s_H[r_1][j0]     = make_float4(Ho[0],Ho[1],Ho[2],Ho[3]);
            *(float4*)&s_H[r_1][j0 + 4] = make_float4(Ho[4],Ho[5],Ho[6],Ho[7]);
        }
    };

    // ---- phase-2 per-thread geometry (fixed across tiles) ----
    constexpr size_t SB = (size_t)NIMG * HOUT * WOUT;  // per-subband stride
    float* __restrict__ o = out + (size_t)img * HOUT * WOUT;
    const int i_  = tid >> 3;          // 0..31 output row in tile
    const int jj_ = (tid & 7) * 4;     // 0,4,...,28 output col in tile

    auto PHASE2 = [&](int t) {
        const int c0 = c0b + t * TO;
        float LLx=0,LLy=0,LLz=0,LLw=0, HLx=0,HLy=0,HLz=0,HLw=0;
        float LHx=0,LHy=0,LHz=0,LHw=0, HHx=0,HHy=0,HHz=0,HHw=0;
        #pragma unroll
        for (int k = 0; k < 5; ++k) {
            float4 a = *(const float4*)&s_L[2*i_ + 2 + k][jj_];
            float4 b = *(const float4*)&s_H[2*i_ + 2 + k][jj_];
            LLx += h0c[k]*a.x; LLy += h0c[k]*a.y; LLz += h0c[k]*a.z; LLw += h0c[k]*a.w;
            HLx += h0c[k]*b.x; HLy += h0c[k]*b.y; HLz += h0c[k]*b.z; HLw += h0c[k]*b.w;
        }
        #pragma unroll
        for (int k = 0; k < 7; ++k) {
            float4 a = *(const float4*)&s_L[2*i_ + k][jj_];
            float4 b = *(const float4*)&s_H[2*i_ + k][jj_];
            LHx += h1c[k]*a.x; LHy += h1c[k]*a.y; LHz += h1c[k]*a.z; LHw += h1c[k]*a.w;
            HHx += h1c[k]*b.x; HHy += h1c[k]*b.y; HHz += h1c[k]*b.z; HHw += h1c[k]*b.w;
        }
        size_t off = (size_t)(r0 + i_) * WOUT + (c0 + jj_);
        *(float4*)(o + 0 * SB + off) = make_float4(LLx, LLy, LLz, LLw);
        *(float4*)(o + 1 * SB + off) = make_float4(LHx, LHy, LHz, LHw);
        *(float4*)(o + 2 * SB + off) = make_float4(HLx, HLy, HLz, HLw);
        *(float4*)(o + 3 * SB + off) = make_float4(HHx, HHy, HHz, HHw);
    };

    // ---- pipeline (single LDS buffer; prefetch carried in registers) ----
    LOAD(0);
    ROWFILT();                 // tile 0 -> LDS (waits on tile-0 loads)
    LOAD(1);                   // tile-1 loads go in flight
    __syncthreads();

    #pragma unroll
    for (int t = 0; t < NT; ++t) {
        PHASE2(t);             // reads LDS; next tile's loads in flight
        if (t + 1 < NT) {
            __syncthreads();   // all reads of LDS done
            ROWFILT();         // consume v -> overwrite LDS with tile t+1
            if (t + 2 < NT) LOAD(t + 2);
            __syncthreads();   // LDS ready
        }
    }
}

extern "C" void kernel_launch(void* const* d_in, const int* in_sizes, int n_in,
                              void* d_out, int out_size, void* d_ws, size_t ws_size,
                              hipStream_t stream) {
    const float* x = (const float*)d_in[0];
    float* out = (float*)d_out;
    dim3 grid(WOUT / (TO * NT), HOUT / TO, NIMG);   // 8 x 16 x 24
    wfb_kernel<<<grid, dim3(256), 0, stream>>>(x, out);
}